// Round 5
// baseline (116.930 us; speedup 1.0000x reference)
//
#include <hip/hip_runtime.h>
#include <hip/hip_bf16.h>

typedef __attribute__((ext_vector_type(8))) short short8;
typedef __attribute__((ext_vector_type(4))) short short4v;
typedef __attribute__((ext_vector_type(4))) float f32x4;
typedef __attribute__((ext_vector_type(16))) float f32x16;

// ws: A' [8192][128] bf16 (2MB) | B' [8192][128] bf16 (2MB) |
//     WoutT [128][1024] bf16 (256KB) | W12bf [64][256] bf16 (32KB)
#define WS_A   0
#define WS_B   (8192 * 128 * 2)
#define WS_WT  (2 * 8192 * 128 * 2)
#define WS_W12 (WS_WT + 128 * 1024 * 2)

static __device__ __forceinline__ short f2bf(float x) {
    __hip_bfloat16 h = __float2bfloat16(x);
    return *reinterpret_cast<short*>(&h);
}

typedef __attribute__((address_space(3))) unsigned int lds_u32;
typedef const __attribute__((address_space(1))) unsigned int glb_u32;
static __device__ __forceinline__ void stage16(const void* g, void* l) {
    __builtin_amdgcn_global_load_lds((glb_u32*)g, (lds_u32*)l, 16, 0, 0);
}

// ---------------- Kernel 0: Wout -> bf16 [z][ck]; W1|W2 -> bf16 [64 c][256 d] ----------------
__global__ __launch_bounds__(256) void k_prep(const float* __restrict__ Wout,
                                              const float* __restrict__ W1,
                                              const float* __restrict__ W2,
                                              __hip_bfloat16* __restrict__ WoutT,
                                              __hip_bfloat16* __restrict__ W12bf) {
    int idx = blockIdx.x * 256 + threadIdx.x;
    if (blockIdx.x < 512) {
        int z = idx >> 10, ck = idx & 1023;
        WoutT[idx] = __float2bfloat16(Wout[ck * 128 + z]);
    } else {
        idx -= 512 * 256;                  // 0..16383
        int c = idx >> 8, d = idx & 255;
        W12bf[idx] = __float2bfloat16(c < 32 ? W1[d * 32 + c] : W2[d * 32 + (c - 32)]);
    }
}

// ---------------- Kernel 1: LayerNorm + dual projection via MFMA (unchanged, verified) --------
__global__ __launch_bounds__(256) void k_lnproj(const float* __restrict__ mm,
                                                const float* __restrict__ gamma,
                                                const float* __restrict__ beta,
                                                const float* __restrict__ b1,
                                                const float* __restrict__ b2,
                                                const __hip_bfloat16* __restrict__ W12bf,
                                                __hip_bfloat16* __restrict__ Ap,
                                                __hip_bfloat16* __restrict__ Bp) {
    __shared__ char sMN[4][8192];      // per-wave [16 rows][256 d] bf16, XOR-swizzled
    const int lane = threadIdx.x & 63;
    const int wid  = threadIdx.x >> 6;
    const int gw   = blockIdx.x * 4 + wid;   // 0..2047
    const int i_   = gw & 255;
    const int sb   = (gw >> 8) * 16;

    float4 g4  = *(const float4*)&gamma[lane * 4];
    float4 be4 = *(const float4*)&beta[lane * 4];
    char* my = sMN[wid];

    #pragma unroll
    for (int rr = 0; rr < 16; rr++) {
        float4 x = *(const float4*)&mm[((size_t)(sb + rr) * 256 + i_) * 256 + lane * 4];
        float s  = x.x + x.y + x.z + x.w;
        float ss = x.x * x.x + x.y * x.y + x.z * x.z + x.w * x.w;
        #pragma unroll
        for (int off = 32; off; off >>= 1) {
            s  += __shfl_xor(s, off);
            ss += __shfl_xor(ss, off);
        }
        float mu  = s * (1.f / 256.f);
        float var = ss * (1.f / 256.f) - mu * mu;
        float rs  = rsqrtf(var + 1e-5f);
        short4v v;
        v.x = f2bf((x.x - mu) * rs * g4.x + be4.x);
        v.y = f2bf((x.y - mu) * rs * g4.y + be4.y);
        v.z = f2bf((x.z - mu) * rs * g4.z + be4.z);
        v.w = f2bf((x.w - mu) * rs * g4.w + be4.w);
        *(short4v*)(my + rr * 512 + ((lane * 8) ^ ((rr & 7) << 4))) = v;
    }

    const short* wt12 = (const short*)W12bf;
    const int g = lane >> 4, r16 = lane & 15;

    f32x4 acc[4];
    #pragma unroll
    for (int nf = 0; nf < 4; nf++) {
        int col = nf * 16 + r16;
        float bv = (col < 32) ? b1[col] : b2[col - 32];
        acc[nf] = (f32x4){bv, bv, bv, bv};
    }
    #pragma unroll
    for (int ks = 0; ks < 8; ks++) {
        int L = ks * 64 + g * 16;
        short8 af = *(const short8*)(my + r16 * 512 + (L ^ ((r16 & 7) << 4)));
        #pragma unroll
        for (int nf = 0; nf < 4; nf++) {
            short8 bfv = *(const short8*)&wt12[(nf * 16 + r16) * 256 + ks * 32 + g * 8];
            acc[nf] = __builtin_amdgcn_mfma_f32_16x16x32_bf16(af, bfv, acc[nf], 0, 0, 0);
        }
    }
    #pragma unroll
    for (int nf = 0; nf < 4; nf++) {
        int col = nf * 16 + r16;
        short* Out = (short*)((col < 32) ? Ap : Bp);
        int cr = col & 31;
        short4v v;
        v.x = f2bf(acc[nf][0]); v.y = f2bf(acc[nf][1]);
        v.z = f2bf(acc[nf][2]); v.w = f2bf(acc[nf][3]);
        *(short4v*)&Out[(i_ * 32 + cr) * 128 + sb + g * 4] = v;
    }
}

// ---------------- Kernel 2: staged O^T GEMM (256x256, K=128) + 2x2x2-split fused epilogue ----
// LDS (128KB dyn): staging [0,64K) kh0 (B|A), [64K,128K) kh1. After main: sP [64 p][2048B].
// sP swizzle: byte = p*2048 + ((gr ^ (p&7))<<4) + sub, gr = ck>>3.
// EPI: 8 waves = im(2 p-halves) x in(2 z-halves) x ik(2 ck-halves), 32x32x16 MFMA,
// cross-wave ik-reduction through LDS at the end.
extern __shared__ char lds[];

__global__ __launch_bounds__(512, 2) void k_gemm5(const __hip_bfloat16* __restrict__ Apb,
                                                  const __hip_bfloat16* __restrict__ Bpb,
                                                  const __hip_bfloat16* __restrict__ WoutT,
                                                  const float* __restrict__ bout,
                                                  float* __restrict__ out) {
    const int t = threadIdx.x, lane = t & 63, wid = t >> 6;
    const int g = lane >> 4, r16 = lane & 15;
    const int wr = wid >> 2, wc = wid & 3;            // wr: jk half (2), wc: ic quarter (4)
    const int bi = blockIdx.x >> 5, bj = blockIdx.x & 31;

    const short* gA = (const short*)Apb + (size_t)bi * 256 * 128;   // ic rows
    const short* gB = (const short*)Bpb + (size_t)bj * 256 * 128;   // jk rows

    // ---- stage both K-halves: 16 x global_load_lds(16B), pre-swizzled source.
    const int srow8 = lane >> 3;
    const int sgran = (lane & 7) ^ srow8;
    #pragma unroll
    for (int kh = 0; kh < 2; kh++) {
        #pragma unroll
        for (int rd = 0; rd < 4; rd++) {
            const int row = rd * 64 + wid * 8 + srow8;
            stage16(gB + row * 128 + kh * 64 + sgran * 8,
                    lds + kh * 65536 + rd * 8192 + wid * 1024);
            stage16(gA + row * 128 + kh * 64 + sgran * 8,
                    lds + kh * 65536 + 32768 + rd * 8192 + wid * 1024);
        }
    }

    asm volatile("s_waitcnt vmcnt(8)" ::: "memory");
    __builtin_amdgcn_s_barrier();

    f32x4 acc[8][4];
    #pragma unroll
    for (int mf = 0; mf < 8; mf++)
        #pragma unroll
        for (int nf = 0; nf < 4; nf++)
            acc[mf][nf] = (f32x4){0.f, 0.f, 0.f, 0.f};

    #pragma unroll
    for (int kh = 0; kh < 2; kh++) {
        if (kh) {
            asm volatile("s_waitcnt vmcnt(0)" ::: "memory");
            __builtin_amdgcn_s_barrier();
        }
        const char* sBb = lds + kh * 65536;
        const char* sAb = lds + kh * 65536 + 32768;
        #pragma unroll
        for (int ksl = 0; ksl < 2; ksl++) {
            short8 af[8], bfv[4];
            #pragma unroll
            for (int mf = 0; mf < 8; mf++) {
                const int row = wr * 128 + mf * 16 + r16;
                af[mf] = *(const short8*)(sBb + row * 128 + (((ksl * 4 + g) ^ (row & 7)) << 4));
            }
            #pragma unroll
            for (int nf = 0; nf < 4; nf++) {
                const int row = wc * 64 + nf * 16 + r16;
                bfv[nf] = *(const short8*)(sAb + row * 128 + (((ksl * 4 + g) ^ (row & 7)) << 4));
            }
            __builtin_amdgcn_s_setprio(1);
            #pragma unroll
            for (int mf = 0; mf < 8; mf++)
                #pragma unroll
                for (int nf = 0; nf < 4; nf++)
                    acc[mf][nf] = __builtin_amdgcn_mfma_f32_16x16x32_bf16(af[mf], bfv[nf], acc[mf][nf], 0, 0, 0);
            __builtin_amdgcn_s_setprio(0);
        }
    }
    __builtin_amdgcn_s_barrier();     // all A/B LDS reads done; sP may overwrite

    // ---- repack ALL acc -> sP[64 p][1024 ck] bf16, b64 writes
    char* sP = lds;
    #pragma unroll
    for (int nf = 0; nf < 4; nf++) {
        const int i_loc = wc * 2 + (nf >> 1);
        #pragma unroll
        for (int mf = 0; mf < 8; mf++) {
            const int p  = i_loc * 8 + wr * 4 + (mf >> 1);
            const int eb = (nf & 1) * 512 + r16 * 32 + (mf & 1) * 16 + g * 4;  // elem in row
            const int gr = eb >> 3;
            const int byte = p * 2048 + (((gr ^ (p & 7)) << 4)) + ((eb & 7) << 1);
            short4v v;
            v.x = f2bf(acc[mf][nf][0]); v.y = f2bf(acc[mf][nf][1]);
            v.z = f2bf(acc[mf][nf][2]); v.w = f2bf(acc[mf][nf][3]);
            *(short4v*)(sP + byte) = v;
        }
    }
    asm volatile("s_waitcnt lgkmcnt(0)" ::: "memory");
    __builtin_amdgcn_s_barrier();     // sP complete

    // ---- epilogue: wave = (im, in_, ik); 32x32x16, M=32 p-rows, N=2x32 z, K=512 slice
    const int im = wid >> 2, in_ = (wid >> 1) & 1, ik = wid & 1;
    const int l31 = lane & 31, kg = lane >> 5;
    const int prow = im * 32 + l31;
    const char* sProw = sP + prow * 2048;
    const int rsw = (prow & 7) << 4;
    const short* wt0 = (const short*)WoutT + (in_ * 64 + l31) * 1024;

    f32x16 e0 = {0,0,0,0,0,0,0,0,0,0,0,0,0,0,0,0};
    f32x16 e1 = {0,0,0,0,0,0,0,0,0,0,0,0,0,0,0,0};
    #pragma unroll 8
    for (int ks = 0; ks < 32; ks++) {
        const int ckb = ik * 512 + ks * 16 + kg * 8;
        short8 pa = *(const short8*)(sProw + (((ckb >> 3) << 4) ^ rsw));
        short8 w0 = *(const short8*)&wt0[ckb];
        short8 w1 = *(const short8*)&wt0[32 * 1024 + ckb];
        e0 = __builtin_amdgcn_mfma_f32_32x32x16_bf16(pa, w0, e0, 0, 0, 0);
        e1 = __builtin_amdgcn_mfma_f32_32x32x16_bf16(pa, w1, e1, 0, 0, 0);
    }

    asm volatile("s_waitcnt lgkmcnt(0)" ::: "memory");
    __builtin_amdgcn_s_barrier();     // all EPI sP reads done; reuse sP for reduction

    const int q = wid >> 1;           // 0..3: (im,in_) pair id
    char* rbuf = sP + q * 8192 + lane * 128;
    if (ik) {
        #pragma unroll
        for (int c = 0; c < 4; c++) {
            f32x4 v0 = {e0[c*4+0], e0[c*4+1], e0[c*4+2], e0[c*4+3]};
            f32x4 v1 = {e1[c*4+0], e1[c*4+1], e1[c*4+2], e1[c*4+3]};
            *(f32x4*)(rbuf + (((c    ) ^ (lane & 7)) << 4)) = v0;
            *(f32x4*)(rbuf + (((c + 4) ^ (lane & 7)) << 4)) = v1;
        }
    }
    asm volatile("s_waitcnt lgkmcnt(0)" ::: "memory");
    __builtin_amdgcn_s_barrier();

    if (!ik) {
        float eS[32];
        #pragma unroll
        for (int c = 0; c < 4; c++) {
            f32x4 v0 = *(const f32x4*)(rbuf + (((c    ) ^ (lane & 7)) << 4));
            f32x4 v1 = *(const f32x4*)(rbuf + (((c + 4) ^ (lane & 7)) << 4));
            #pragma unroll
            for (int j = 0; j < 4; j++) {
                eS[c * 4 + j]      = e0[c * 4 + j] + v0[j];
                eS[16 + c * 4 + j] = e1[c * 4 + j] + v1[j];
            }
        }
        #pragma unroll
        for (int nf = 0; nf < 2; nf++) {
            const int z  = in_ * 64 + nf * 32 + l31;
            const float bv = bout[z];
            #pragma unroll
            for (int r = 0; r < 16; r++) {
                const int p  = im * 32 + (r & 3) + 8 * (r >> 2) + 4 * kg;
                const int ig = bi * 8 + (p >> 3), jg = bj * 8 + (p & 7);
                out[((size_t)(ig * 256 + jg)) * 128 + z] = (eS[nf * 16 + r] + bv) * (1.f / 128.f);
            }
        }
    }
}

extern "C" void kernel_launch(void* const* d_in, const int* in_sizes, int n_in,
                              void* d_out, int out_size, void* d_ws, size_t ws_size,
                              hipStream_t stream) {
    const float* mm    = (const float*)d_in[0];
    const float* gamma = (const float*)d_in[1];
    const float* beta  = (const float*)d_in[2];
    const float* W1    = (const float*)d_in[3];
    const float* b1    = (const float*)d_in[4];
    const float* W2    = (const float*)d_in[5];
    const float* b2    = (const float*)d_in[6];
    const float* Wout  = (const float*)d_in[7];
    const float* bout  = (const float*)d_in[8];

    __hip_bfloat16* Ap    = (__hip_bfloat16*)((char*)d_ws + WS_A);
    __hip_bfloat16* Bp    = (__hip_bfloat16*)((char*)d_ws + WS_B);
    __hip_bfloat16* WoutT = (__hip_bfloat16*)((char*)d_ws + WS_WT);
    __hip_bfloat16* W12bf = (__hip_bfloat16*)((char*)d_ws + WS_W12);
    float* out = (float*)d_out;

    (void)hipFuncSetAttribute(reinterpret_cast<const void*>(k_gemm5),
                              hipFuncAttributeMaxDynamicSharedMemorySize, 131072);

    hipLaunchKernelGGL(k_prep, dim3(576), dim3(256), 0, stream, Wout, W1, W2, WoutT, W12bf);
    hipLaunchKernelGGL(k_lnproj, dim3(512), dim3(256), 0, stream,
                       mm, gamma, beta, b1, b2, W12bf, Ap, Bp);
    hipLaunchKernelGGL(k_gemm5, dim3(1024), dim3(512), 131072, stream,
                       Ap, Bp, WoutT, bout, out);
}

// Round 6
// 71.513 us; speedup vs baseline: 1.6351x; 1.6351x over previous
//
#include <hip/hip_runtime.h>
#include <hip/hip_bf16.h>

typedef __attribute__((ext_vector_type(8))) short short8;
typedef __attribute__((ext_vector_type(4))) short short4v;
typedef __attribute__((ext_vector_type(4))) float f32x4;

// ws: A' [8192][128] bf16 (2MB) | B' [8192][128] bf16 (2MB) |
//     WoutT [128][1024] bf16 (256KB) | W12bf [64][256] bf16 (32KB)
#define WS_A   0
#define WS_B   (8192 * 128 * 2)
#define WS_WT  (2 * 8192 * 128 * 2)
#define WS_W12 (WS_WT + 128 * 1024 * 2)

static __device__ __forceinline__ short f2bf(float x) {
    __hip_bfloat16 h = __float2bfloat16(x);
    return *reinterpret_cast<short*>(&h);
}

typedef __attribute__((address_space(3))) unsigned int lds_u32;
typedef const __attribute__((address_space(1))) unsigned int glb_u32;
static __device__ __forceinline__ void stage16(const void* g, void* l) {
    __builtin_amdgcn_global_load_lds((glb_u32*)g, (lds_u32*)l, 16, 0, 0);
}

// ---------------- Kernel 0: Wout -> bf16 [z][ck]; W1|W2 -> bf16 [64 c][256 d] ----------------
__global__ __launch_bounds__(256) void k_prep(const float* __restrict__ Wout,
                                              const float* __restrict__ W1,
                                              const float* __restrict__ W2,
                                              __hip_bfloat16* __restrict__ WoutT,
                                              __hip_bfloat16* __restrict__ W12bf) {
    int idx = blockIdx.x * 256 + threadIdx.x;
    if (blockIdx.x < 512) {
        int z = idx >> 10, ck = idx & 1023;
        WoutT[idx] = __float2bfloat16(Wout[ck * 128 + z]);
    } else {
        idx -= 512 * 256;                  // 0..16383
        int c = idx >> 8, d = idx & 255;
        W12bf[idx] = __float2bfloat16(c < 32 ? W1[d * 32 + c] : W2[d * 32 + (c - 32)]);
    }
}

// ---------------- Kernel 1: LayerNorm + dual projection via MFMA ----------------
// W12 staged in swizzled LDS (removes per-iter global latency in the MFMA loop).
__global__ __launch_bounds__(256) void k_lnproj(const float* __restrict__ mm,
                                                const float* __restrict__ gamma,
                                                const float* __restrict__ beta,
                                                const float* __restrict__ b1,
                                                const float* __restrict__ b2,
                                                const __hip_bfloat16* __restrict__ W12bf,
                                                __hip_bfloat16* __restrict__ Ap,
                                                __hip_bfloat16* __restrict__ Bp) {
    __shared__ char sMN[4][8192];      // per-wave [16 rows][256 d] bf16, XOR-swizzled
    __shared__ char sW[32768];         // [64 c][256 d] bf16, XOR-swizzled (512B rows)
    const int t    = threadIdx.x;
    const int lane = t & 63;
    const int wid  = t >> 6;
    const int gw   = blockIdx.x * 4 + wid;   // 0..2047
    const int i_   = gw & 255;
    const int sb   = (gw >> 8) * 16;

    // stage W12 -> sW (32KB): 2048 chunks of 16B
    #pragma unroll
    for (int it = 0; it < 8; it++) {
        const int idx = it * 256 + t;
        const int row = idx >> 5;
        const int L   = (idx & 31) * 16;
        *(short8*)(sW + row * 512 + (L ^ ((row & 7) << 4))) =
            *(const short8*)((const short*)W12bf + idx * 8);
    }

    float4 g4  = *(const float4*)&gamma[lane * 4];
    float4 be4 = *(const float4*)&beta[lane * 4];
    char* my = sMN[wid];

    #pragma unroll
    for (int rr = 0; rr < 16; rr++) {
        float4 x = *(const float4*)&mm[((size_t)(sb + rr) * 256 + i_) * 256 + lane * 4];
        float s  = x.x + x.y + x.z + x.w;
        float ss = x.x * x.x + x.y * x.y + x.z * x.z + x.w * x.w;
        #pragma unroll
        for (int off = 32; off; off >>= 1) {
            s  += __shfl_xor(s, off);
            ss += __shfl_xor(ss, off);
        }
        float mu  = s * (1.f / 256.f);
        float var = ss * (1.f / 256.f) - mu * mu;
        float rs  = rsqrtf(var + 1e-5f);
        short4v v;
        v.x = f2bf((x.x - mu) * rs * g4.x + be4.x);
        v.y = f2bf((x.y - mu) * rs * g4.y + be4.y);
        v.z = f2bf((x.z - mu) * rs * g4.z + be4.z);
        v.w = f2bf((x.w - mu) * rs * g4.w + be4.w);
        *(short4v*)(my + rr * 512 + ((lane * 8) ^ ((rr & 7) << 4))) = v;
    }
    __syncthreads();                   // sW visible (sMN is wave-local anyway)

    const int g = lane >> 4, r16 = lane & 15;

    f32x4 acc[4];
    #pragma unroll
    for (int nf = 0; nf < 4; nf++) {
        int col = nf * 16 + r16;
        float bv = (col < 32) ? b1[col] : b2[col - 32];
        acc[nf] = (f32x4){bv, bv, bv, bv};
    }
    #pragma unroll
    for (int ks = 0; ks < 8; ks++) {
        const int L = ks * 64 + g * 16;
        short8 af = *(const short8*)(my + r16 * 512 + (L ^ ((r16 & 7) << 4)));
        #pragma unroll
        for (int nf = 0; nf < 4; nf++) {
            short8 bfv = *(const short8*)(sW + (nf * 16 + r16) * 512 + (L ^ ((r16 & 7) << 4)));
            acc[nf] = __builtin_amdgcn_mfma_f32_16x16x32_bf16(af, bfv, acc[nf], 0, 0, 0);
        }
    }
    #pragma unroll
    for (int nf = 0; nf < 4; nf++) {
        int col = nf * 16 + r16;
        short* Out = (short*)((col < 32) ? Ap : Bp);
        int cr = col & 31;
        short4v v;
        v.x = f2bf(acc[nf][0]); v.y = f2bf(acc[nf][1]);
        v.z = f2bf(acc[nf][2]); v.w = f2bf(acc[nf][3]);
        *(short4v*)&Out[(i_ * 32 + cr) * 128 + sb + g * 4] = v;
    }
}

// ---------------- Kernel 2: staged O^T GEMM (256x256, K=128) + pipelined fused epilogue ----
// LDS (128KB dyn): staging kh0 [0,64K) (B|A), kh1 [64K,128K). After main: sP h0 [0,64K),
// sP h1 [64K,128K) ([64 p][512 ck'] each, key ((L>>7)^p)&7).
// EPI: z-split (wave owns 16 z), W prefetched in 2 rolling register groups.
extern __shared__ char lds[];

__global__ __launch_bounds__(512, 1) void k_gemm6(const __hip_bfloat16* __restrict__ Apb,
                                                  const __hip_bfloat16* __restrict__ Bpb,
                                                  const __hip_bfloat16* __restrict__ WoutT,
                                                  const float* __restrict__ bout,
                                                  float* __restrict__ out) {
    const int t = threadIdx.x, lane = t & 63, wid = t >> 6;
    const int g = lane >> 4, r16 = lane & 15;
    const int wr = wid >> 2, wc = wid & 3;            // wr: jk half (2), wc: ic quarter (4)
    const int bid = (blockIdx.x & 7) * 128 + (blockIdx.x >> 3);   // XCD swizzle (1024%8==0)
    const int bi = bid >> 5, bj = bid & 31;

    const short* gA = (const short*)Apb + (size_t)bi * 256 * 128;   // ic rows
    const short* gB = (const short*)Bpb + (size_t)bj * 256 * 128;   // jk rows

    // ---- stage both K-halves: 16 x global_load_lds(16B), pre-swizzled source.
    const int srow8 = lane >> 3;
    const int sgran = (lane & 7) ^ srow8;
    #pragma unroll
    for (int kh = 0; kh < 2; kh++) {
        #pragma unroll
        for (int rd = 0; rd < 4; rd++) {
            const int row = rd * 64 + wid * 8 + srow8;
            stage16(gB + row * 128 + kh * 64 + sgran * 8,
                    lds + kh * 65536 + rd * 8192 + wid * 1024);
            stage16(gA + row * 128 + kh * 64 + sgran * 8,
                    lds + kh * 65536 + 32768 + rd * 8192 + wid * 1024);
        }
    }

    asm volatile("s_waitcnt vmcnt(8)" ::: "memory");
    __builtin_amdgcn_s_barrier();

    f32x4 acc[8][4];
    #pragma unroll
    for (int mf = 0; mf < 8; mf++)
        #pragma unroll
        for (int nf = 0; nf < 4; nf++)
            acc[mf][nf] = (f32x4){0.f, 0.f, 0.f, 0.f};

    #pragma unroll
    for (int kh = 0; kh < 2; kh++) {
        if (kh) {
            asm volatile("s_waitcnt vmcnt(0)" ::: "memory");
            __builtin_amdgcn_s_barrier();
        }
        const char* sBb = lds + kh * 65536;
        const char* sAb = lds + kh * 65536 + 32768;
        #pragma unroll
        for (int ksl = 0; ksl < 2; ksl++) {
            short8 af[8], bfv[4];
            #pragma unroll
            for (int mf = 0; mf < 8; mf++) {
                const int row = wr * 128 + mf * 16 + r16;
                af[mf] = *(const short8*)(sBb + row * 128 + (((ksl * 4 + g) ^ (row & 7)) << 4));
            }
            #pragma unroll
            for (int nf = 0; nf < 4; nf++) {
                const int row = wc * 64 + nf * 16 + r16;
                bfv[nf] = *(const short8*)(sAb + row * 128 + (((ksl * 4 + g) ^ (row & 7)) << 4));
            }
            __builtin_amdgcn_s_setprio(1);
            #pragma unroll
            for (int mf = 0; mf < 8; mf++)
                #pragma unroll
                for (int nf = 0; nf < 4; nf++)
                    acc[mf][nf] = __builtin_amdgcn_mfma_f32_16x16x32_bf16(af[mf], bfv[nf], acc[mf][nf], 0, 0, 0);
            __builtin_amdgcn_s_setprio(0);
        }
    }
    __builtin_amdgcn_s_barrier();     // all A/B LDS reads done; sP may overwrite

    // epilogue accumulators: z = wid*16 + r16
    const int z = wid * 16 + r16;
    const float bv = bout[z];
    f32x4 acc2[4];
    #pragma unroll
    for (int pf = 0; pf < 4; pf++) acc2[pf] = (f32x4){bv, bv, bv, bv};
    const short* wtz = (const short*)WoutT + z * 1024 + g * 8;

    short8 wA[4], wB[4];

    // ---- W prefetch group (4 ks of 32 ck): h in {0,1}, grp in {0..3}
    #define WLOAD(buf, h, grp)                                                           \
        {                                                                                \
            _Pragma("unroll")                                                            \
            for (int q = 0; q < 4; q++)                                                  \
                buf[q] = *(const short8*)&wtz[(h) * 512 + ((grp) * 4 + q) * 32];         \
        }

    // ---- EPI compute for one group (4 ks x 4 pf MFMA) off sP half h
    #define WCOMP(buf, h, grp)                                                           \
        {                                                                                \
            const char* sPh = lds + (h) * 65536;                                         \
            __builtin_amdgcn_s_setprio(1);                                               \
            _Pragma("unroll")                                                            \
            for (int q = 0; q < 4; q++) {                                                \
                const int L = ((grp) * 4 + q) * 64 + g * 16;                             \
                _Pragma("unroll")                                                        \
                for (int pf = 0; pf < 4; pf++) {                                         \
                    const int row = pf * 16 + r16;                                       \
                    short8 pv = *(const short8*)(sPh + row * 1024 +                      \
                                                 (L ^ ((((L >> 7) ^ row) & 7) << 4)));   \
                    acc2[pf] = __builtin_amdgcn_mfma_f32_16x16x32_bf16(pv, buf[q], acc2[pf], 0, 0, 0); \
                }                                                                        \
            }                                                                            \
            __builtin_amdgcn_s_setprio(0);                                               \
        }

    // ---- repack half h into sP[h]: p = i_loc*8 + j_loc, ck' = r16*32 + (mf&1)*16 + g*4 + reg
    #define REPACK(h)                                                                    \
        {                                                                                \
            char* sPh = lds + (h) * 65536;                                               \
            _Pragma("unroll")                                                            \
            for (int nq = 0; nq < 2; nq++) {                                             \
                const int nf = (h) + nq * 2;                                             \
                const int p = (wc * 2 + nq) * 8 + wr * 4;                                \
                _Pragma("unroll")                                                        \
                for (int mf = 0; mf < 8; mf++) {                                         \
                    const int pp = p + (mf >> 1);                                        \
                    const int L = r16 * 64 + (mf & 1) * 32 + g * 8;                      \
                    short4v v;                                                           \
                    v.x = f2bf(acc[mf][nf][0]); v.y = f2bf(acc[mf][nf][1]);              \
                    v.z = f2bf(acc[mf][nf][2]); v.w = f2bf(acc[mf][nf][3]);              \
                    *(short4v*)(sPh + pp * 1024 + (L ^ ((((L >> 7) ^ pp) & 7) << 4))) = v; \
                }                                                                        \
            }                                                                            \
        }

    WLOAD(wA, 0, 0)
    WLOAD(wB, 0, 1)
    REPACK(0)
    asm volatile("s_waitcnt lgkmcnt(0)" ::: "memory");
    __builtin_amdgcn_s_barrier();     // sP h0 visible
    REPACK(1)                          // h1 writes overlap h0 EPI

    WCOMP(wA, 0, 0) WLOAD(wA, 0, 2)
    WCOMP(wB, 0, 1) WLOAD(wB, 0, 3)
    WCOMP(wA, 0, 2) WLOAD(wA, 1, 0)
    WCOMP(wB, 0, 3) WLOAD(wB, 1, 1)

    asm volatile("s_waitcnt lgkmcnt(0)" ::: "memory");
    __builtin_amdgcn_s_barrier();     // sP h1 visible

    WCOMP(wA, 1, 0) WLOAD(wA, 1, 2)
    WCOMP(wB, 1, 1) WLOAD(wB, 1, 3)
    WCOMP(wA, 1, 2)
    WCOMP(wB, 1, 3)

    #pragma unroll
    for (int pf = 0; pf < 4; pf++) {
        #pragma unroll
        for (int reg = 0; reg < 4; reg++) {
            const int p = pf * 16 + g * 4 + reg;
            const int ig = bi * 8 + (p >> 3), jg = bj * 8 + (p & 7);
            out[((size_t)(ig * 256 + jg)) * 128 + z] = acc2[pf][reg] * (1.f / 128.f);
        }
    }
    #undef REPACK
    #undef WLOAD
    #undef WCOMP
}

extern "C" void kernel_launch(void* const* d_in, const int* in_sizes, int n_in,
                              void* d_out, int out_size, void* d_ws, size_t ws_size,
                              hipStream_t stream) {
    const float* mm    = (const float*)d_in[0];
    const float* gamma = (const float*)d_in[1];
    const float* beta  = (const float*)d_in[2];
    const float* W1    = (const float*)d_in[3];
    const float* b1    = (const float*)d_in[4];
    const float* W2    = (const float*)d_in[5];
    const float* b2    = (const float*)d_in[6];
    const float* Wout  = (const float*)d_in[7];
    const float* bout  = (const float*)d_in[8];

    __hip_bfloat16* Ap    = (__hip_bfloat16*)((char*)d_ws + WS_A);
    __hip_bfloat16* Bp    = (__hip_bfloat16*)((char*)d_ws + WS_B);
    __hip_bfloat16* WoutT = (__hip_bfloat16*)((char*)d_ws + WS_WT);
    __hip_bfloat16* W12bf = (__hip_bfloat16*)((char*)d_ws + WS_W12);
    float* out = (float*)d_out;

    (void)hipFuncSetAttribute(reinterpret_cast<const void*>(k_gemm6),
                              hipFuncAttributeMaxDynamicSharedMemorySize, 131072);

    hipLaunchKernelGGL(k_prep, dim3(576), dim3(256), 0, stream, Wout, W1, W2, WoutT, W12bf);
    hipLaunchKernelGGL(k_lnproj, dim3(512), dim3(256), 0, stream,
                       mm, gamma, beta, b1, b2, W12bf, Ap, Bp);
    hipLaunchKernelGGL(k_gemm6, dim3(1024), dim3(512), 131072, stream,
                       Ap, Bp, WoutT, bout, out);
}